// Round 3
// baseline (359.557 us; speedup 1.0000x reference)
//
#include <hip/hip_runtime.h>
#include <math.h>

#define BB   1024
#define FF   1024
#define NOUT 512
#define NW   256
#define RT   8      // rows per thread (= rows per block)
#define KC   8      // k chunk per iteration (single-buffered, TLP-hidden)
#define NTILE 256   // 128 row-blocks x 2 col-halves

typedef float f4 __attribute__((ext_vector_type(4)));

__device__ int g_cnt[NTILE];   // .bss zeroed at load; monotonic tickets mod ks

template<bool ERO>
__device__ __forceinline__ void core(
    const float* __restrict__ x,
    const float* __restrict__ w,
    float* __restrict__ out,
    float* __restrict__ ws,
    const int ks, const int ch)
{
    const int tid  = threadIdx.x;      // column within the 256-col half
    const int by   = blockIdx.y;
    const int bz   = blockIdx.z;
    const int row0 = by * RT;
    const int fstart = bz * ch;
    const float* __restrict__ wcol = w + tid;   // per-lane column base (coalesced)

    // Per-row element offsets, pinned into VGPRs -> formally divergent ->
    // guaranteed VMEM (global_load saddr+voffset), never re-scalarized.
    int rb[RT];
#pragma unroll
    for (int r = 0; r < RT; ++r) {
        rb[r] = r * FF;
        asm("" : "+v"(rb[r]));
    }

    float acc[RT];
#pragma unroll
    for (int r = 0; r < RT; ++r) acc[r] = -INFINITY;

    const float* xbase = x + (size_t)row0 * FF + fstart;  // uniform (SGPR) part
    const int nchunk = ch / KC;

#pragma unroll 1
    for (int kc = 0; kc < nchunk; ++kc) {
        const float* bp = xbase + kc * KC;   // uniform advance
        const int fb = fstart + kc * KC;

        // x chunk: 8 rows x 8 k, in-order VMEM, broadcast across lanes
        f4 xv0[RT], xv1[RT];
#pragma unroll
        for (int r = 0; r < RT; ++r) {
            xv0[r] = *(const f4*)(bp + rb[r]);        // k 0..3
            xv1[r] = *(const f4*)(bp + rb[r] + 4);    // k 4..7
        }
        // w chunk: per-lane coalesced b32
        float wv[KC];
#pragma unroll
        for (int k = 0; k < KC; ++k)
            wv[k] = wcol[(size_t)(fb + k) * NW];

#pragma unroll
        for (int k = 0; k < KC; k += 2) {
#pragma unroll
            for (int r = 0; r < RT; ++r) {
                const float x0 = (k < 4) ? xv0[r][k & 3]       : xv1[r][k & 3];
                const float x1 = (k < 4) ? xv0[r][(k + 1) & 3] : xv1[r][(k + 1) & 3];
                const float t0 = ERO ? (wv[k]     - x0) : (x0 + wv[k]);
                const float t1 = ERO ? (wv[k + 1] - x1) : (x1 + wv[k + 1]);
                acc[r] = fmaxf(acc[r], fmaxf(t0, t1));   // -> v_max3_f32
            }
        }
    }

    // bias row f=FF: x contribution is 0 -> just the weight value
    if (bz == ks - 1) {
        const float wb = wcol[(size_t)FF * NW];
#pragma unroll
        for (int r = 0; r < RT; ++r) acc[r] = fmaxf(acc[r], wb);
    }

    float res[RT];
#pragma unroll
    for (int r = 0; r < RT; ++r) res[r] = ERO ? -acc[r] : acc[r];

    const int col = (ERO ? 0 : NW) + tid;

    if (ks == 1) {
#pragma unroll
        for (int r = 0; r < RT; ++r)
            out[(size_t)(row0 + r) * NOUT + col] = res[r];
        return;
    }

    // write this K-slice's partial
    {
        float* p = ws + (size_t)bz * (BB * NOUT);
#pragma unroll
        for (int r = 0; r < RT; ++r)
            p[(size_t)(row0 + r) * NOUT + col] = res[r];
    }

    // last-arrival block of this tile reduces all ks slices (fused combine)
    __threadfence();                     // release partials (device scope)
    __shared__ int s_last;
    if (tid == 0) {
        const int tile = by * 2 + (ERO ? 0 : 1);
        const int old = atomicAdd(&g_cnt[tile], 1);
        s_last = (((old + 1) & (ks - 1)) == 0) ? 1 : 0;   // ks is pow2
    }
    __syncthreads();
    if (!s_last) return;
    __threadfence();                     // acquire others' partials

    for (int z = 0; z < ks; ++z) {
        if (z == bz) continue;
        const float* p = ws + (size_t)z * (BB * NOUT);
#pragma unroll
        for (int r = 0; r < RT; ++r) {
            const float u = p[(size_t)(row0 + r) * NOUT + col];
            res[r] = ERO ? fminf(res[r], u) : fmaxf(res[r], u);
        }
    }
#pragma unroll
    for (int r = 0; r < RT; ++r)
        out[(size_t)(row0 + r) * NOUT + col] = res[r];
}

__global__ __launch_bounds__(256, 5) void trop_main(
    const float* __restrict__ x,
    const float* __restrict__ dil,
    const float* __restrict__ ero,
    float* __restrict__ out,
    float* __restrict__ ws,
    const int ks, const int ch)
{
    if (blockIdx.x == 0) core<true >(x, ero, out, ws, ks, ch);
    else                 core<false>(x, dil, out, ws, ks, ch);
}

extern "C" void kernel_launch(void* const* d_in, const int* in_sizes, int n_in,
                              void* d_out, int out_size, void* d_ws, size_t ws_size,
                              hipStream_t stream) {
    const float* x   = (const float*)d_in[0];
    const float* dil = (const float*)d_in[1];
    const float* ero = (const float*)d_in[2];
    float* out = (float*)d_out;

    const size_t outbytes = (size_t)BB * NOUT * sizeof(float);
    int ks = 1;
    if      (ws_size >= 8 * outbytes) ks = 8;
    else if (ws_size >= 4 * outbytes) ks = 4;
    else if (ws_size >= 2 * outbytes) ks = 2;

    dim3 grid(2, BB / RT, ks);
    trop_main<<<grid, 256, 0, stream>>>(x, dil, ero, out, (float*)d_ws, ks, FF / ks);
}

// Round 4
// 258.173 us; speedup vs baseline: 1.3927x; 1.3927x over previous
//
#include <hip/hip_runtime.h>
#include <math.h>

#define BB    1024
#define FF    1024
#define NOUT  512
#define NW    256
#define BT    64     // rows per block tile
#define NT    64     // cols per block tile
#define KT    32     // k per LDS chunk
#define NTILE 128    // (NOUT/NT) * (BB/BT) output tiles

__device__ int g_cnt[NTILE];   // .bss zeroed at load; monotonic tickets mod ks (pow2-safe)

// 128 threads: cg = tid&7 (8 col-groups x 8 cols), rg = tid>>3 (16 row-groups x 4 rows)
template<bool ERO>
__device__ __forceinline__ void core(
    float (* __restrict__ lds_x)[BT],
    float (* __restrict__ lds_w)[NT],
    const float* __restrict__ x,
    const float* __restrict__ w,
    float* __restrict__ out,
    float* __restrict__ ws,
    const int c0w, const int ks, const int ch)
{
    const int tid = threadIdx.x;
    const int cg  = tid & 7;
    const int rg  = tid >> 3;
    const int by  = blockIdx.y;
    const int bz  = blockIdx.z;
    const int r0  = by * BT;

    float acc[4][8];
#pragma unroll
    for (int i = 0; i < 4; ++i)
#pragma unroll
        for (int j = 0; j < 8; ++j) acc[i][j] = -INFINITY;

    const int fstart = bz * ch;
    const int nchunk = ch / KT;

    for (int kc = 0; kc < nchunk; ++kc) {
        const int fb = fstart + kc * KT;
        if (kc) __syncthreads();

        // ---- stage x^T (64 rows x 32 k): 512 float4, 4 per thread ----
#pragma unroll
        for (int it = 0; it < 4; ++it) {
            const int idx = tid + it * 128;
            const int r   = idx & 63;
            const int g   = idx >> 6;             // 0..7 -> k-group of 4
            const float4 v = *(const float4*)(x + (size_t)(r0 + r) * FF + fb + g * 4);
            lds_x[g * 4 + 0][r] = v.x;
            lds_x[g * 4 + 1][r] = v.y;
            lds_x[g * 4 + 2][r] = v.z;
            lds_x[g * 4 + 3][r] = v.w;
        }
        // ---- stage w (32 k x 64 cols), natural layout ----
#pragma unroll
        for (int it = 0; it < 4; ++it) {
            const int idx = tid + it * 128;
            const int f   = idx >> 4;             // 0..31
            const int c4  = idx & 15;             // 0..15
            *(float4*)&lds_w[f][c4 * 4] =
                *(const float4*)(w + (size_t)(fb + f) * NW + c0w + c4 * 4);
        }
        __syncthreads();

        // ---- max-plus / max-minus inner loop, K-unrolled by 2 for v_max3 ----
#pragma unroll
        for (int ff = 0; ff < KT; ff += 2) {
            const float4 x0  = *(const float4*)&lds_x[ff][rg << 2];
            const float4 x1  = *(const float4*)&lds_x[ff + 1][rg << 2];
            const float4 wa0 = *(const float4*)&lds_w[ff][cg << 3];
            const float4 wb0 = *(const float4*)&lds_w[ff][(cg << 3) + 4];
            const float4 wa1 = *(const float4*)&lds_w[ff + 1][cg << 3];
            const float4 wb1 = *(const float4*)&lds_w[ff + 1][(cg << 3) + 4];
            const float xr0[4] = {x0.x, x0.y, x0.z, x0.w};
            const float xr1[4] = {x1.x, x1.y, x1.z, x1.w};
            const float wc0[8] = {wa0.x, wa0.y, wa0.z, wa0.w, wb0.x, wb0.y, wb0.z, wb0.w};
            const float wc1[8] = {wa1.x, wa1.y, wa1.z, wa1.w, wb1.x, wb1.y, wb1.z, wb1.w};
#pragma unroll
            for (int i = 0; i < 4; ++i)
#pragma unroll
                for (int j = 0; j < 8; ++j) {
                    const float t0 = ERO ? (wc0[j] - xr0[i]) : (xr0[i] + wc0[j]);
                    const float t1 = ERO ? (wc1[j] - xr1[i]) : (xr1[i] + wc1[j]);
                    acc[i][j] = fmaxf(acc[i][j], fmaxf(t0, t1));
                }
        }
    }

    // ---- bias row f=FF: x contribution 0 -> weight value feeds the max ----
    if (bz == ks - 1) {
        const float4 ba = *(const float4*)(w + (size_t)FF * NW + c0w + (cg << 3));
        const float4 bb = *(const float4*)(w + (size_t)FF * NW + c0w + (cg << 3) + 4);
        const float bc[8] = {ba.x, ba.y, ba.z, ba.w, bb.x, bb.y, bb.z, bb.w};
#pragma unroll
        for (int i = 0; i < 4; ++i)
#pragma unroll
            for (int j = 0; j < 8; ++j) acc[i][j] = fmaxf(acc[i][j], bc[j]);
    }

    // ---- negate for erosion (min(x-e) = -max(e-x)) ----
    float res[4][8];
#pragma unroll
    for (int i = 0; i < 4; ++i)
#pragma unroll
        for (int j = 0; j < 8; ++j) res[i][j] = ERO ? -acc[i][j] : acc[i][j];

    const int cglob = blockIdx.x * NT + (cg << 3);

    if (ks == 1) {
#pragma unroll
        for (int i = 0; i < 4; ++i) {
            const int row = r0 + (rg << 2) + i;
            *(float4*)(out + (size_t)row * NOUT + cglob)     = *(float4*)&res[i][0];
            *(float4*)(out + (size_t)row * NOUT + cglob + 4) = *(float4*)&res[i][4];
        }
        return;
    }

    // ---- write this K-slice's partial ----
    {
        float* p = ws + (size_t)bz * (BB * NOUT);
#pragma unroll
        for (int i = 0; i < 4; ++i) {
            const int row = r0 + (rg << 2) + i;
            *(float4*)(p + (size_t)row * NOUT + cglob)     = *(float4*)&res[i][0];
            *(float4*)(p + (size_t)row * NOUT + cglob + 4) = *(float4*)&res[i][4];
        }
    }

    // ---- last-arrival block of this tile reduces all ks slices ----
    __threadfence();                       // release partials (device scope)
    __shared__ int s_last;
    if (tid == 0) {
        const int tile = by * gridDim.x + blockIdx.x;   // < NTILE
        const int old = atomicAdd(&g_cnt[tile], 1);
        s_last = (((old + 1) & (ks - 1)) == 0) ? 1 : 0; // ks is pow2
    }
    __syncthreads();
    if (!s_last) return;
    __threadfence();                       // acquire others' partials

    for (int z = 0; z < ks; ++z) {
        if (z == bz) continue;
        const float* p = ws + (size_t)z * (BB * NOUT);
#pragma unroll
        for (int i = 0; i < 4; ++i) {
            const int row = r0 + (rg << 2) + i;
            const float4 u0 = *(const float4*)(p + (size_t)row * NOUT + cglob);
            const float4 u1 = *(const float4*)(p + (size_t)row * NOUT + cglob + 4);
            const float u[8] = {u0.x, u0.y, u0.z, u0.w, u1.x, u1.y, u1.z, u1.w};
#pragma unroll
            for (int j = 0; j < 8; ++j)
                res[i][j] = ERO ? fminf(res[i][j], u[j]) : fmaxf(res[i][j], u[j]);
        }
    }
#pragma unroll
    for (int i = 0; i < 4; ++i) {
        const int row = r0 + (rg << 2) + i;
        *(float4*)(out + (size_t)row * NOUT + cglob)     = *(float4*)&res[i][0];
        *(float4*)(out + (size_t)row * NOUT + cglob + 4) = *(float4*)&res[i][4];
    }
}

__global__ __launch_bounds__(128, 4) void trop_main(
    const float* __restrict__ x,
    const float* __restrict__ dil,
    const float* __restrict__ ero,
    float* __restrict__ out,
    float* __restrict__ ws,
    const int ks, const int ch)
{
    __shared__ float lds_x[KT][BT];
    __shared__ float lds_w[KT][NT];
    const int bx = blockIdx.x;
    if (bx < NW / NT) {
        core<true >(lds_x, lds_w, x, ero, out, ws, bx * NT,      ks, ch);
    } else {
        core<false>(lds_x, lds_w, x, dil, out, ws, bx * NT - NW, ks, ch);
    }
}

extern "C" void kernel_launch(void* const* d_in, const int* in_sizes, int n_in,
                              void* d_out, int out_size, void* d_ws, size_t ws_size,
                              hipStream_t stream) {
    const float* x   = (const float*)d_in[0];
    const float* dil = (const float*)d_in[1];
    const float* ero = (const float*)d_in[2];
    float* out = (float*)d_out;

    const size_t outbytes = (size_t)BB * NOUT * sizeof(float);
    int ks = 1;
    if      (ws_size >= 16 * outbytes) ks = 16;
    else if (ws_size >=  8 * outbytes) ks = 8;
    else if (ws_size >=  4 * outbytes) ks = 4;
    else if (ws_size >=  2 * outbytes) ks = 2;

    dim3 grid(NOUT / NT, BB / BT, ks);
    trop_main<<<grid, 128, 0, stream>>>(x, dil, ero, out, (float*)d_ws, ks, FF / ks);
}